// Round 19
// baseline (206.830 us; speedup 1.0000x reference)
//
#include <hip/hip_runtime.h>
#include <cstddef>
#include <cstdint>

#define NN   100000   // nodes
#define NR   4        // relations
#define NE   160000   // edges per relation
#define GEMMB 1024    // gemm vblocks in phaseB (256 per relation)
#define VB1  256      // vblocks per relation, layer-1 gemm
#define VB2  512      // vblocks per pair, layer-2 dual gemm

typedef short bf16x8 __attribute__((ext_vector_type(8)));
typedef float f32x4  __attribute__((ext_vector_type(4)));

__device__ __forceinline__ unsigned short f2bf(float f) {  // RNE f32->bf16
  union { float f; unsigned u; } v; v.f = f;
  unsigned r = v.u + 0x7fffu + ((v.u >> 16) & 1u);
  return (unsigned short)(r >> 16);
}
__device__ __forceinline__ float bf2f(unsigned short h) {
  union { unsigned u; float f; } v; v.u = ((unsigned)h) << 16;
  return v.f;
}

// async global->LDS, 16B per lane, linear LDS dest
__device__ __forceinline__ void gll16(const unsigned short* g, unsigned short* l) {
  __builtin_amdgcn_global_load_lds(
      (const __attribute__((address_space(1))) void*)g,
      (__attribute__((address_space(3))) void*)l, 16, 0, 0);
}

// ---------------------------------------------------------------- phase A: zero 800k ints + converts
#define A_ZERO 782
#define A_NBLK (A_ZERO + 6250 + 256 + 128 + 1)  // 7417
__global__ __launch_bounds__(256) void phaseA_k(const float* __restrict__ x,
                                                const float* __restrict__ W1,
                                                const float* __restrict__ W2,
                                                const float* __restrict__ b1,
                                                const float* __restrict__ b2,
                                                int* __restrict__ zbase,    // cnt_out|cursor4, 2*NR*NN ints
                                                unsigned short* __restrict__ xb,
                                                unsigned short* __restrict__ Wt1,
                                                unsigned short* __restrict__ Wt2,
                                                float* __restrict__ bs1,
                                                float* __restrict__ bs2) {
  const int bid = blockIdx.x;
  const int t = threadIdx.x;
  if (bid < A_ZERO) {
    const int i = bid * 256 + t;
    if (i < 2 * NR * NN / 4) ((int4*)zbase)[i] = make_int4(0, 0, 0, 0);
  } else if (bid < A_ZERO + 6250) {  // cvtx
    const int i = (bid - A_ZERO) * 256 + t;
    const float4 a = *(const float4*)&x[(size_t)i * 8];
    const float4 b = *(const float4*)&x[(size_t)i * 8 + 4];
    unsigned short o[8];
    o[0] = f2bf(a.x); o[1] = f2bf(a.y); o[2] = f2bf(a.z); o[3] = f2bf(a.w);
    o[4] = f2bf(b.x); o[5] = f2bf(b.y); o[6] = f2bf(b.z); o[7] = f2bf(b.w);
    *(bf16x8*)&xb[(size_t)i * 8] = *(bf16x8*)o;
  } else if (bid < A_ZERO + 6250 + 256) {  // cvtw1
    const int i = (bid - A_ZERO - 6250) * 256 + t;
    const int r = i / (128 * 128);
    const int k = (i / 128) % 128;
    const int n = i % 128;
    Wt1[((size_t)r * 128 + n) * 128 + k] = f2bf(W1[i]);
  } else if (bid < A_ZERO + 6250 + 256 + 128) {  // cvtw2
    const int i = (bid - A_ZERO - 6250 - 256) * 256 + t;
    const int r = i / (128 * 64);
    const int k = (i / 64) % 128;
    const int n = i % 64;
    Wt2[((size_t)r * 64 + n) * 128 + k] = f2bf(W2[i]);
  } else {
    if (t < 128) bs1[t] = b1[t] + b1[128 + t] + b1[256 + t] + b1[384 + t];
    if (t < 64)  bs2[t] = b2[t] + b2[64 + t] + b2[128 + t] + b2[192 + t];
  }
}

// ---------------------------------------------------------------- GEMM core (stride-parametrized)
template <int NOUT>
__device__ __forceinline__ void gemm_core(const unsigned short* __restrict__ Xb,
                                          const unsigned short* __restrict__ Wtr,
                                          unsigned short* __restrict__ Hr,
                                          int vb, int stride,
                                          unsigned short (*Xl)[64 * 128]) {
  const int t = threadIdx.x;
  const int wid = t >> 6;
  const int lane = t & 63;
  const int lg = lane >> 4;
  const int lr = lane & 15;

  constexpr int NF = (NOUT == 128) ? 4 : 2;
  const int rbase = (wid & 1) * 32;
  const int cbase = (wid >> 1) * (NOUT / 2);

  bf16x8 bw[NF][4];
#pragma unroll
  for (int nf = 0; nf < NF; ++nf)
#pragma unroll
    for (int ks = 0; ks < 4; ++ks)
      bw[nf][ks] = *(const bf16x8*)&Wtr[(size_t)(cbase + nf * 16 + lr) * 128 + ks * 32 + lg * 8];

  auto stage = [&](int buf, int tile) {
    const int row0 = tile * 64;
#pragma unroll
    for (int i = 0; i < 4; ++i) {
      const int rl = wid * 16 + i * 4 + (lane >> 4);
      int gr = row0 + rl;
      if (gr >= NN) gr = NN - 1;
      const int q = (lane & 15) ^ (rl & 7);
      gll16(&Xb[(size_t)gr * 128 + q * 8], &Xl[buf][rl * 128 + (lane & 15) * 8]);
    }
  };

  const int ntiles = (NN + 63) / 64;  // 1563
  int tile = vb;
  if (tile >= ntiles) return;
  stage(0, tile);
  __syncthreads();
  int buf = 0;

  for (; tile < ntiles; tile += stride) {
    const int nxt = tile + stride;
    if (nxt < ntiles) stage(buf ^ 1, nxt);

    f32x4 acc[2][NF];
#pragma unroll
    for (int mf = 0; mf < 2; ++mf)
#pragma unroll
      for (int nf = 0; nf < NF; ++nf) acc[mf][nf] = (f32x4){0.f, 0.f, 0.f, 0.f};

#pragma unroll
    for (int ks = 0; ks < 4; ++ks) {
#pragma unroll
      for (int mf = 0; mf < 2; ++mf) {
        const int r = rbase + mf * 16 + lr;
        const bf16x8 a =
            *(const bf16x8*)&Xl[buf][r * 128 + (((ks * 4 + lg) ^ (lr & 7)) << 3)];
#pragma unroll
        for (int nf = 0; nf < NF; ++nf)
          acc[mf][nf] = __builtin_amdgcn_mfma_f32_16x16x32_bf16(a, bw[nf][ks], acc[mf][nf], 0, 0, 0);
      }
    }

    const int row0 = tile * 64;
#pragma unroll
    for (int mf = 0; mf < 2; ++mf) {
#pragma unroll
      for (int i = 0; i < 4; ++i) {
        const int row = row0 + rbase + mf * 16 + lg * 4 + i;
        if (row < NN) {
#pragma unroll
          for (int nf = 0; nf < NF; ++nf)
            Hr[(size_t)row * NOUT + cbase + nf * 16 + lr] = f2bf(acc[mf][nf][i]);
        }
      }
    }
    __syncthreads();
    buf ^= 1;
  }
}

// ---------------------------------------------------------------- dual-relation GEMM core (NOUT=64; stride-parametrized)
__device__ __forceinline__ void gemm_dual_core64(const unsigned short* __restrict__ Xb,
                                                 const unsigned short* __restrict__ W0,
                                                 const unsigned short* __restrict__ W1,
                                                 unsigned short* __restrict__ H0,
                                                 unsigned short* __restrict__ H1,
                                                 int vb, int stride,
                                                 unsigned short (*Xl)[64 * 128]) {
  const int t = threadIdx.x;
  const int wid = t >> 6;
  const int lane = t & 63;
  const int lg = lane >> 4;
  const int lr = lane & 15;

  const int rbase = (wid & 1) * 32;
  const int cbase = (wid >> 1) * 32;

  bf16x8 bw[2][2][4];
#pragma unroll
  for (int nf = 0; nf < 2; ++nf)
#pragma unroll
    for (int ks = 0; ks < 4; ++ks) {
      bw[0][nf][ks] = *(const bf16x8*)&W0[(size_t)(cbase + nf * 16 + lr) * 128 + ks * 32 + lg * 8];
      bw[1][nf][ks] = *(const bf16x8*)&W1[(size_t)(cbase + nf * 16 + lr) * 128 + ks * 32 + lg * 8];
    }

  auto stage = [&](int buf, int tile) {
    const int row0 = tile * 64;
#pragma unroll
    for (int i = 0; i < 4; ++i) {
      const int rl = wid * 16 + i * 4 + (lane >> 4);
      int gr = row0 + rl;
      if (gr >= NN) gr = NN - 1;
      const int q = (lane & 15) ^ (rl & 7);
      gll16(&Xb[(size_t)gr * 128 + q * 8], &Xl[buf][rl * 128 + (lane & 15) * 8]);
    }
  };

  const int ntiles = (NN + 63) / 64;  // 1563
  int tile = vb;
  if (tile >= ntiles) return;
  stage(0, tile);
  __syncthreads();
  int buf = 0;

  for (; tile < ntiles; tile += stride) {
    const int nxt = tile + stride;
    if (nxt < ntiles) stage(buf ^ 1, nxt);

    f32x4 acc[2][2][2];
#pragma unroll
    for (int mf = 0; mf < 2; ++mf)
#pragma unroll
      for (int rel = 0; rel < 2; ++rel)
#pragma unroll
        for (int nf = 0; nf < 2; ++nf) acc[mf][rel][nf] = (f32x4){0.f, 0.f, 0.f, 0.f};

#pragma unroll
    for (int ks = 0; ks < 4; ++ks) {
#pragma unroll
      for (int mf = 0; mf < 2; ++mf) {
        const int r = rbase + mf * 16 + lr;
        const bf16x8 a =
            *(const bf16x8*)&Xl[buf][r * 128 + (((ks * 4 + lg) ^ (lr & 7)) << 3)];
#pragma unroll
        for (int rel = 0; rel < 2; ++rel)
#pragma unroll
          for (int nf = 0; nf < 2; ++nf)
            acc[mf][rel][nf] = __builtin_amdgcn_mfma_f32_16x16x32_bf16(a, bw[rel][nf][ks], acc[mf][rel][nf], 0, 0, 0);
      }
    }

    const int row0 = tile * 64;
#pragma unroll
    for (int mf = 0; mf < 2; ++mf) {
#pragma unroll
      for (int i = 0; i < 4; ++i) {
        const int row = row0 + rbase + mf * 16 + lg * 4 + i;
        if (row < NN) {
#pragma unroll
          for (int nf = 0; nf < 2; ++nf) {
            H0[(size_t)row * 64 + cbase + nf * 16 + lr] = f2bf(acc[mf][0][nf][i]);
            H1[(size_t)row * 64 + cbase + nf * 16 + lr] = f2bf(acc[mf][1][nf][i]);
          }
        }
      }
    }
    __syncthreads();
    buf ^= 1;
  }
}

__global__ __launch_bounds__(256, 2) void gemm_dual_k(const unsigned short* __restrict__ Xb,
                                                      const unsigned short* __restrict__ Wt,
                                                      unsigned short* __restrict__ H) {
  __shared__ unsigned short Xl[2][64 * 128];
  const int zp = blockIdx.z;
  gemm_dual_core64(Xb,
                   Wt + (size_t)(2 * zp) * 64 * 128,
                   Wt + (size_t)(2 * zp + 1) * 64 * 128,
                   H + (size_t)(2 * zp) * NN * 64,
                   H + (size_t)(2 * zp + 1) * NN * 64,
                   blockIdx.x, VB2, Xl);
}

// ---------------------------------------------------------------- phaseB: gemm1 || prep (count + ELL insert)
__global__ __launch_bounds__(256, 2) void phaseB_ell_k(const int* __restrict__ edges,
                                                       const unsigned short* __restrict__ xb,
                                                       const unsigned short* __restrict__ Wt1,
                                                       unsigned short* __restrict__ H,
                                                       int* __restrict__ cnt_out,
                                                       int* __restrict__ cursor4,
                                                       int* __restrict__ ell) {
  __shared__ unsigned short Xl[2][64 * 128];
  const int bid = blockIdx.x;
  if (bid < GEMMB) {
    const int z = bid >> 8;           // 256 vblocks per relation
    gemm_core<128>(xb, Wt1 + (size_t)z * 128 * 128, H + (size_t)z * NN * 128,
                   bid & (VB1 - 1), VB1, Xl);
    return;
  }
  const int idx = bid - GEMMB;
  const int r = idx / 625;
  const int e = (idx - r * 625) * 256 + threadIdx.x;
  const int s = edges[(size_t)r * 2 * NE + e];
  const int d = edges[(size_t)r * 2 * NE + NE + e];
  atomicAdd(&cnt_out[(size_t)r * NN + s], 1);
  const int pos = atomicAdd(&cursor4[d * 4 + r], 1);
  if (pos < 16) ell[(size_t)d * 64 + r * 16 + pos] = s;
}

// ---------------------------------------------------------------- gather1e (R18 verbatim)
__global__ __launch_bounds__(256) void gather1e_k(const unsigned short* __restrict__ H,
                                                  const int* __restrict__ cnt_out,
                                                  const int* __restrict__ cursor4,
                                                  const int* __restrict__ ell,
                                                  const float* __restrict__ bs1,
                                                  unsigned short* __restrict__ h1b) {
  const int node = blockIdx.x * 4 + (threadIdx.x >> 6);
  const int lane = threadIdx.x & 63;
  const int g  = lane >> 4;
  const int fl = lane & 15;

  const int4 c4 = *(const int4*)&cursor4[node * 4];
  const int rel = lane >> 4;
  const int idx = lane & 15;
  const int cr = (rel == 0) ? c4.x : (rel == 1) ? c4.y : (rel == 2) ? c4.z : c4.w;
  const int nslots = cr < 16 ? cr : 16;
  const bool valid = idx < nslots;

  int row = 0;
  float w = 0.f;
  if (valid) {
    const int src = ell[(size_t)node * 64 + lane];
    row = rel * NN + src;
    w = rsqrtf(fmaxf((float)cnt_out[row], 1.f)) * rsqrtf(fmaxf((float)cr, 1.f));
  }

  const unsigned long long mask = __ballot(valid);
  const int total = __popcll(mask);
  const int pos = __popcll(mask & ((1ull << lane) - 1ull));
  const int tgt = (valid ? pos : 63) << 2;
  const int crow = __builtin_amdgcn_ds_permute(tgt, row);
  const int cwb  = __builtin_amdgcn_ds_permute(tgt, __float_as_int(w));

  float acc[8];
#pragma unroll
  for (int j = 0; j < 8; ++j) acc[j] = 0.f;

  const int kmax = (total + 3) >> 2;  // wave-uniform
  for (int k = 0; k < kmax; ++k) {
    const int e = g + k * 4;
    const int rowe = __shfl(crow, e);
    const float we = __int_as_float(__shfl(cwb, e));
    if (e < total) {
      const bf16x8 h = *(const bf16x8*)&H[(size_t)rowe * 128 + fl * 8];
#pragma unroll
      for (int j = 0; j < 8; ++j)
        acc[j] = fmaf(bf2f((unsigned short)h[j]), we, acc[j]);
    }
  }
#pragma unroll
  for (int j = 0; j < 8; ++j) {
    acc[j] += __shfl_xor(acc[j], 16);
    acc[j] += __shfl_xor(acc[j], 32);
  }
  if (g == 0) {
    const float4 c0 = *(const float4*)&bs1[fl * 8];
    const float4 c1 = *(const float4*)&bs1[fl * 8 + 4];
    unsigned short o[8];
    o[0] = f2bf(fmaxf(acc[0] + c0.x, 0.f));
    o[1] = f2bf(fmaxf(acc[1] + c0.y, 0.f));
    o[2] = f2bf(fmaxf(acc[2] + c0.z, 0.f));
    o[3] = f2bf(fmaxf(acc[3] + c0.w, 0.f));
    o[4] = f2bf(fmaxf(acc[4] + c1.x, 0.f));
    o[5] = f2bf(fmaxf(acc[5] + c1.y, 0.f));
    o[6] = f2bf(fmaxf(acc[6] + c1.z, 0.f));
    o[7] = f2bf(fmaxf(acc[7] + c1.w, 0.f));
    *(bf16x8*)&h1b[(size_t)node * 128 + fl * 8] = *(bf16x8*)o;
  }
}

// ---------------------------------------------------------------- gather2e (R18 verbatim)
__global__ __launch_bounds__(256) void gather2e_k(const unsigned short* __restrict__ H,
                                                  const int* __restrict__ cnt_out,
                                                  const int* __restrict__ cursor4,
                                                  const int* __restrict__ ell,
                                                  const float* __restrict__ bs2,
                                                  float* __restrict__ out) {
  const int node = blockIdx.x * 4 + (threadIdx.x >> 6);
  const int lane = threadIdx.x & 63;
  const int g  = lane >> 3;
  const int fl = lane & 7;

  const int4 c4 = *(const int4*)&cursor4[node * 4];
  const int rel = lane >> 4;
  const int idx = lane & 15;
  const int cr = (rel == 0) ? c4.x : (rel == 1) ? c4.y : (rel == 2) ? c4.z : c4.w;
  const int nslots = cr < 16 ? cr : 16;
  const bool valid = idx < nslots;

  int row = 0;
  float w = 0.f;
  if (valid) {
    const int src = ell[(size_t)node * 64 + lane];
    row = rel * NN + src;
    w = rsqrtf(fmaxf((float)cnt_out[row], 1.f)) * rsqrtf(fmaxf((float)cr, 1.f));
  }

  const unsigned long long mask = __ballot(valid);
  const int total = __popcll(mask);
  const int pos = __popcll(mask & ((1ull << lane) - 1ull));
  const int tgt = (valid ? pos : 63) << 2;
  const int crow = __builtin_amdgcn_ds_permute(tgt, row);
  const int cwb  = __builtin_amdgcn_ds_permute(tgt, __float_as_int(w));

  float acc[8];
#pragma unroll
  for (int j = 0; j < 8; ++j) acc[j] = 0.f;

  const int kmax = (total + 7) >> 3;  // wave-uniform
  for (int k = 0; k < kmax; ++k) {
    const int e = g + k * 8;
    const int rowe = __shfl(crow, e);
    const float we = __int_as_float(__shfl(cwb, e));
    if (e < total) {
      const bf16x8 h = *(const bf16x8*)&H[(size_t)rowe * 64 + fl * 8];
#pragma unroll
      for (int j = 0; j < 8; ++j)
        acc[j] = fmaf(bf2f((unsigned short)h[j]), we, acc[j]);
    }
  }
#pragma unroll
  for (int j = 0; j < 8; ++j) {
    acc[j] += __shfl_xor(acc[j], 8);
    acc[j] += __shfl_xor(acc[j], 16);
    acc[j] += __shfl_xor(acc[j], 32);
  }
  if (g == 0) {
    const float4 c0 = *(const float4*)&bs2[fl * 8];
    const float4 c1 = *(const float4*)&bs2[fl * 8 + 4];
    float4 o0, o1;
    o0.x = acc[0] + c0.x; o0.y = acc[1] + c0.y; o0.z = acc[2] + c0.z; o0.w = acc[3] + c0.w;
    o1.x = acc[4] + c1.x; o1.y = acc[5] + c1.y; o1.z = acc[6] + c1.z; o1.w = acc[7] + c1.w;
    *(float4*)&out[(size_t)node * 64 + fl * 8]     = o0;
    *(float4*)&out[(size_t)node * 64 + fl * 8 + 4] = o1;
  }
}

// ---------------------------------------------------------------- launch
extern "C" void kernel_launch(void* const* d_in, const int* in_sizes, int n_in,
                              void* d_out, int out_size, void* d_ws, size_t ws_size,
                              hipStream_t stream) {
  const float* x     = (const float*)d_in[0];
  const int*   edges = (const int*)d_in[1];
  const float* W1    = (const float*)d_in[2];
  const float* b1    = (const float*)d_in[3];
  const float* W2    = (const float*)d_in[4];
  const float* b2    = (const float*)d_in[5];
  float* out = (float*)d_out;

  // ---- workspace layout (R18 ELL, proven)
  unsigned short* xb   = (unsigned short*)d_ws;            // NN*128 bf16
  unsigned short* h1b  = xb;
  unsigned short* Hbuf = xb + (size_t)NN * 128;            // NR*NN*128 bf16
  unsigned short* Wt1  = Hbuf + (size_t)NR * NN * 128;     // NR*128*128 bf16
  unsigned short* Wt2  = Wt1 + (size_t)NR * 128 * 128;     // NR*64*128 bf16
  int* cnt_out  = (int*)(Wt2 + (size_t)NR * 64 * 128);     // NR*NN
  int* cursor4  = cnt_out + (size_t)NR * NN;               // NN*4
  float* bs1    = (float*)(cursor4 + (size_t)NN * 4);      // 128
  float* bs2    = bs1 + 128;                               // 64
  int* ell      = (int*)(bs2 + 64);                        // NN*64

  // A) zero cnt_out+cursor4 + converts + bias sums
  phaseA_k<<<A_NBLK, 256, 0, stream>>>(x, W1, W2, b1, b2, cnt_out, xb, Wt1, Wt2, bs1, bs2);
  // B) gemm1 (1024 vblocks, 4/CU) || prep (count + ELL insert)
  phaseB_ell_k<<<GEMMB + 2500, 256, 0, stream>>>(edges, xb, Wt1, Hbuf, cnt_out, cursor4, ell);
  // C) gather+bias+relu -> h1b
  gather1e_k<<<NN / 4, 256, 0, stream>>>(Hbuf, cnt_out, cursor4, ell, bs1, h1b);
  // D) layer-2 dual GEMM (1024 blocks, 4/CU)
  gemm_dual_k<<<dim3(VB2, 1, 2), 256, 0, stream>>>(h1b, Wt2, Hbuf);
  // E) gather+bias -> out
  gather2e_k<<<NN / 4, 256, 0, stream>>>(Hbuf, cnt_out, cursor4, ell, bs2, out);
}

// Round 20
// 193.917 us; speedup vs baseline: 1.0666x; 1.0666x over previous
//
#include <hip/hip_runtime.h>
#include <cstddef>
#include <cstdint>

#define NN   100000   // nodes
#define NR   4        // relations
#define NE   160000   // edges per relation
#define GEMMB 512     // gemm vblocks in phaseB (128 per relation)

typedef short bf16x8 __attribute__((ext_vector_type(8)));
typedef float f32x4  __attribute__((ext_vector_type(4)));

__device__ __forceinline__ unsigned short f2bf(float f) {  // RNE f32->bf16
  union { float f; unsigned u; } v; v.f = f;
  unsigned r = v.u + 0x7fffu + ((v.u >> 16) & 1u);
  return (unsigned short)(r >> 16);
}
__device__ __forceinline__ float bf2f(unsigned short h) {
  union { unsigned u; float f; } v; v.u = ((unsigned)h) << 16;
  return v.f;
}

// async global->LDS, 16B per lane, linear LDS dest
__device__ __forceinline__ void gll16(const unsigned short* g, unsigned short* l) {
  __builtin_amdgcn_global_load_lds(
      (const __attribute__((address_space(1))) void*)g,
      (__attribute__((address_space(3))) void*)l, 16, 0, 0);
}

// ---------------------------------------------------------------- phase A: zero 800k ints + converts
#define A_ZERO 782
#define A_NBLK (A_ZERO + 6250 + 256 + 128 + 1)  // 7417
__global__ __launch_bounds__(256) void phaseA_k(const float* __restrict__ x,
                                                const float* __restrict__ W1,
                                                const float* __restrict__ W2,
                                                const float* __restrict__ b1,
                                                const float* __restrict__ b2,
                                                int* __restrict__ zbase,    // cnt_out|cursor4, 2*NR*NN ints
                                                unsigned short* __restrict__ xb,
                                                unsigned short* __restrict__ Wt1,
                                                unsigned short* __restrict__ Wt2,
                                                float* __restrict__ bs1,
                                                float* __restrict__ bs2) {
  const int bid = blockIdx.x;
  const int t = threadIdx.x;
  if (bid < A_ZERO) {
    const int i = bid * 256 + t;
    if (i < 2 * NR * NN / 4) ((int4*)zbase)[i] = make_int4(0, 0, 0, 0);
  } else if (bid < A_ZERO + 6250) {  // cvtx
    const int i = (bid - A_ZERO) * 256 + t;
    const float4 a = *(const float4*)&x[(size_t)i * 8];
    const float4 b = *(const float4*)&x[(size_t)i * 8 + 4];
    unsigned short o[8];
    o[0] = f2bf(a.x); o[1] = f2bf(a.y); o[2] = f2bf(a.z); o[3] = f2bf(a.w);
    o[4] = f2bf(b.x); o[5] = f2bf(b.y); o[6] = f2bf(b.z); o[7] = f2bf(b.w);
    *(bf16x8*)&xb[(size_t)i * 8] = *(bf16x8*)o;
  } else if (bid < A_ZERO + 6250 + 256) {  // cvtw1
    const int i = (bid - A_ZERO - 6250) * 256 + t;
    const int r = i / (128 * 128);
    const int k = (i / 128) % 128;
    const int n = i % 128;
    Wt1[((size_t)r * 128 + n) * 128 + k] = f2bf(W1[i]);
  } else if (bid < A_ZERO + 6250 + 256 + 128) {  // cvtw2
    const int i = (bid - A_ZERO - 6250 - 256) * 256 + t;
    const int r = i / (128 * 64);
    const int k = (i / 64) % 128;
    const int n = i % 64;
    Wt2[((size_t)r * 64 + n) * 128 + k] = f2bf(W2[i]);
  } else {
    if (t < 128) bs1[t] = b1[t] + b1[128 + t] + b1[256 + t] + b1[384 + t];
    if (t < 64)  bs2[t] = b2[t] + b2[64 + t] + b2[128 + t] + b2[192 + t];
  }
}

// ---------------------------------------------------------------- GEMM core
template <int NOUT>
__device__ __forceinline__ void gemm_core(const unsigned short* __restrict__ Xb,
                                          const unsigned short* __restrict__ Wtr,
                                          unsigned short* __restrict__ Hr,
                                          int vb, unsigned short (*Xl)[64 * 128]) {
  const int t = threadIdx.x;
  const int wid = t >> 6;
  const int lane = t & 63;
  const int lg = lane >> 4;
  const int lr = lane & 15;

  constexpr int NF = (NOUT == 128) ? 4 : 2;
  const int rbase = (wid & 1) * 32;
  const int cbase = (wid >> 1) * (NOUT / 2);

  bf16x8 bw[NF][4];
#pragma unroll
  for (int nf = 0; nf < NF; ++nf)
#pragma unroll
    for (int ks = 0; ks < 4; ++ks)
      bw[nf][ks] = *(const bf16x8*)&Wtr[(size_t)(cbase + nf * 16 + lr) * 128 + ks * 32 + lg * 8];

  auto stage = [&](int buf, int tile) {
    const int row0 = tile * 64;
#pragma unroll
    for (int i = 0; i < 4; ++i) {
      const int rl = wid * 16 + i * 4 + (lane >> 4);
      int gr = row0 + rl;
      if (gr >= NN) gr = NN - 1;
      const int q = (lane & 15) ^ (rl & 7);
      gll16(&Xb[(size_t)gr * 128 + q * 8], &Xl[buf][rl * 128 + (lane & 15) * 8]);
    }
  };

  const int ntiles = (NN + 63) / 64;  // 1563
  int tile = vb;
  stage(0, tile);
  __syncthreads();
  int buf = 0;

  for (; tile < ntiles; tile += 128) {
    const int nxt = tile + 128;
    if (nxt < ntiles) stage(buf ^ 1, nxt);

    f32x4 acc[2][NF];
#pragma unroll
    for (int mf = 0; mf < 2; ++mf)
#pragma unroll
      for (int nf = 0; nf < NF; ++nf) acc[mf][nf] = (f32x4){0.f, 0.f, 0.f, 0.f};

#pragma unroll
    for (int ks = 0; ks < 4; ++ks) {
#pragma unroll
      for (int mf = 0; mf < 2; ++mf) {
        const int r = rbase + mf * 16 + lr;
        const bf16x8 a =
            *(const bf16x8*)&Xl[buf][r * 128 + (((ks * 4 + lg) ^ (lr & 7)) << 3)];
#pragma unroll
        for (int nf = 0; nf < NF; ++nf)
          acc[mf][nf] = __builtin_amdgcn_mfma_f32_16x16x32_bf16(a, bw[nf][ks], acc[mf][nf], 0, 0, 0);
      }
    }

    const int row0 = tile * 64;
#pragma unroll
    for (int mf = 0; mf < 2; ++mf) {
#pragma unroll
      for (int i = 0; i < 4; ++i) {
        const int row = row0 + rbase + mf * 16 + lg * 4 + i;
        if (row < NN) {
#pragma unroll
          for (int nf = 0; nf < NF; ++nf)
            Hr[(size_t)row * NOUT + cbase + nf * 16 + lr] = f2bf(acc[mf][nf][i]);
        }
      }
    }
    __syncthreads();
    buf ^= 1;
  }
}

// ---------------------------------------------------------------- dual-relation GEMM core (NOUT=64)
__device__ __forceinline__ void gemm_dual_core64(const unsigned short* __restrict__ Xb,
                                                 const unsigned short* __restrict__ W0,
                                                 const unsigned short* __restrict__ W1,
                                                 unsigned short* __restrict__ H0,
                                                 unsigned short* __restrict__ H1,
                                                 int vb, unsigned short (*Xl)[64 * 128]) {
  const int t = threadIdx.x;
  const int wid = t >> 6;
  const int lane = t & 63;
  const int lg = lane >> 4;
  const int lr = lane & 15;

  const int rbase = (wid & 1) * 32;
  const int cbase = (wid >> 1) * 32;

  bf16x8 bw[2][2][4];
#pragma unroll
  for (int nf = 0; nf < 2; ++nf)
#pragma unroll
    for (int ks = 0; ks < 4; ++ks) {
      bw[0][nf][ks] = *(const bf16x8*)&W0[(size_t)(cbase + nf * 16 + lr) * 128 + ks * 32 + lg * 8];
      bw[1][nf][ks] = *(const bf16x8*)&W1[(size_t)(cbase + nf * 16 + lr) * 128 + ks * 32 + lg * 8];
    }

  auto stage = [&](int buf, int tile) {
    const int row0 = tile * 64;
#pragma unroll
    for (int i = 0; i < 4; ++i) {
      const int rl = wid * 16 + i * 4 + (lane >> 4);
      int gr = row0 + rl;
      if (gr >= NN) gr = NN - 1;
      const int q = (lane & 15) ^ (rl & 7);
      gll16(&Xb[(size_t)gr * 128 + q * 8], &Xl[buf][rl * 128 + (lane & 15) * 8]);
    }
  };

  const int ntiles = (NN + 63) / 64;  // 1563
  int tile = vb;
  stage(0, tile);
  __syncthreads();
  int buf = 0;

  for (; tile < ntiles; tile += 128) {
    const int nxt = tile + 128;
    if (nxt < ntiles) stage(buf ^ 1, nxt);

    f32x4 acc[2][2][2];
#pragma unroll
    for (int mf = 0; mf < 2; ++mf)
#pragma unroll
      for (int rel = 0; rel < 2; ++rel)
#pragma unroll
        for (int nf = 0; nf < 2; ++nf) acc[mf][rel][nf] = (f32x4){0.f, 0.f, 0.f, 0.f};

#pragma unroll
    for (int ks = 0; ks < 4; ++ks) {
#pragma unroll
      for (int mf = 0; mf < 2; ++mf) {
        const int r = rbase + mf * 16 + lr;
        const bf16x8 a =
            *(const bf16x8*)&Xl[buf][r * 128 + (((ks * 4 + lg) ^ (lr & 7)) << 3)];
#pragma unroll
        for (int rel = 0; rel < 2; ++rel)
#pragma unroll
          for (int nf = 0; nf < 2; ++nf)
            acc[mf][rel][nf] = __builtin_amdgcn_mfma_f32_16x16x32_bf16(a, bw[rel][nf][ks], acc[mf][rel][nf], 0, 0, 0);
      }
    }

    const int row0 = tile * 64;
#pragma unroll
    for (int mf = 0; mf < 2; ++mf) {
#pragma unroll
      for (int i = 0; i < 4; ++i) {
        const int row = row0 + rbase + mf * 16 + lg * 4 + i;
        if (row < NN) {
#pragma unroll
          for (int nf = 0; nf < 2; ++nf) {
            H0[(size_t)row * 64 + cbase + nf * 16 + lr] = f2bf(acc[mf][0][nf][i]);
            H1[(size_t)row * 64 + cbase + nf * 16 + lr] = f2bf(acc[mf][1][nf][i]);
          }
        }
      }
    }
    __syncthreads();
    buf ^= 1;
  }
}

__global__ __launch_bounds__(256, 2) void gemm_dual_k(const unsigned short* __restrict__ Xb,
                                                      const unsigned short* __restrict__ Wt,
                                                      unsigned short* __restrict__ H) {
  __shared__ unsigned short Xl[2][64 * 128];
  const int zp = blockIdx.z;
  gemm_dual_core64(Xb,
                   Wt + (size_t)(2 * zp) * 64 * 128,
                   Wt + (size_t)(2 * zp + 1) * 64 * 128,
                   H + (size_t)(2 * zp) * NN * 64,
                   H + (size_t)(2 * zp + 1) * NN * 64,
                   blockIdx.x, Xl);
}

// ---------------------------------------------------------------- phaseB: gemm1 || prep (count + ELL insert)
__global__ __launch_bounds__(256, 2) void phaseB_ell_k(const int* __restrict__ edges,
                                                       const unsigned short* __restrict__ xb,
                                                       const unsigned short* __restrict__ Wt1,
                                                       unsigned short* __restrict__ H,
                                                       int* __restrict__ cnt_out,
                                                       int* __restrict__ cursor4,
                                                       int* __restrict__ ell) {
  __shared__ unsigned short Xl[2][64 * 128];
  const int bid = blockIdx.x;
  if (bid < GEMMB) {
    const int z = bid >> 7;
    gemm_core<128>(xb, Wt1 + (size_t)z * 128 * 128, H + (size_t)z * NN * 128, bid & 127, Xl);
    return;
  }
  const int idx = bid - GEMMB;
  const int r = idx / 625;
  const int e = (idx - r * 625) * 256 + threadIdx.x;
  const int s = edges[(size_t)r * 2 * NE + e];
  const int d = edges[(size_t)r * 2 * NE + NE + e];
  atomicAdd(&cnt_out[(size_t)r * NN + s], 1);
  const int pos = atomicAdd(&cursor4[d * 4 + r], 1);
  if (pos < 16) ell[(size_t)d * 64 + r * 16 + pos] = s;
}

// ---------------------------------------------------------------- gather1e
// Per wave = 1 node. Lane l owns slot l (rel=l>>4, idx=l&15). Weight computed
// per-lane (all lanes converged), compacted via push ds_permute, then
// uniform-trip shfl loop (4 groups x 16 lanes).
__global__ __launch_bounds__(256) void gather1e_k(const unsigned short* __restrict__ H,
                                                  const int* __restrict__ cnt_out,
                                                  const int* __restrict__ cursor4,
                                                  const int* __restrict__ ell,
                                                  const float* __restrict__ bs1,
                                                  unsigned short* __restrict__ h1b) {
  const int node = blockIdx.x * 4 + (threadIdx.x >> 6);
  const int lane = threadIdx.x & 63;
  const int g  = lane >> 4;
  const int fl = lane & 15;

  const int4 c4 = *(const int4*)&cursor4[node * 4];
  const int rel = lane >> 4;
  const int idx = lane & 15;
  const int cr = (rel == 0) ? c4.x : (rel == 1) ? c4.y : (rel == 2) ? c4.z : c4.w;
  const int nslots = cr < 16 ? cr : 16;
  const bool valid = idx < nslots;

  int row = 0;
  float w = 0.f;
  if (valid) {
    const int src = ell[(size_t)node * 64 + lane];
    row = rel * NN + src;
    w = rsqrtf(fmaxf((float)cnt_out[row], 1.f)) * rsqrtf(fmaxf((float)cr, 1.f));
  }

  // compaction (all 64 lanes active)
  const unsigned long long mask = __ballot(valid);
  const int total = __popcll(mask);
  const int pos = __popcll(mask & ((1ull << lane) - 1ull));
  const int tgt = (valid ? pos : 63) << 2;
  const int crow = __builtin_amdgcn_ds_permute(tgt, row);
  const int cwb  = __builtin_amdgcn_ds_permute(tgt, __float_as_int(w));

  float acc[8];
#pragma unroll
  for (int j = 0; j < 8; ++j) acc[j] = 0.f;

  const int kmax = (total + 3) >> 2;  // wave-uniform trip count
  for (int k = 0; k < kmax; ++k) {
    const int e = g + k * 4;          // <= 63 always
    const int rowe = __shfl(crow, e);
    const float we = __int_as_float(__shfl(cwb, e));
    if (e < total) {
      const bf16x8 h = *(const bf16x8*)&H[(size_t)rowe * 128 + fl * 8];
#pragma unroll
      for (int j = 0; j < 8; ++j)
        acc[j] = fmaf(bf2f((unsigned short)h[j]), we, acc[j]);
    }
  }
#pragma unroll
  for (int j = 0; j < 8; ++j) {
    acc[j] += __shfl_xor(acc[j], 16);
    acc[j] += __shfl_xor(acc[j], 32);
  }
  if (g == 0) {
    const float4 c0 = *(const float4*)&bs1[fl * 8];
    const float4 c1 = *(const float4*)&bs1[fl * 8 + 4];
    unsigned short o[8];
    o[0] = f2bf(fmaxf(acc[0] + c0.x, 0.f));
    o[1] = f2bf(fmaxf(acc[1] + c0.y, 0.f));
    o[2] = f2bf(fmaxf(acc[2] + c0.z, 0.f));
    o[3] = f2bf(fmaxf(acc[3] + c0.w, 0.f));
    o[4] = f2bf(fmaxf(acc[4] + c1.x, 0.f));
    o[5] = f2bf(fmaxf(acc[5] + c1.y, 0.f));
    o[6] = f2bf(fmaxf(acc[6] + c1.z, 0.f));
    o[7] = f2bf(fmaxf(acc[7] + c1.w, 0.f));
    *(bf16x8*)&h1b[(size_t)node * 128 + fl * 8] = *(bf16x8*)o;
  }
}

// ---------------------------------------------------------------- gather2e
__global__ __launch_bounds__(256) void gather2e_k(const unsigned short* __restrict__ H,
                                                  const int* __restrict__ cnt_out,
                                                  const int* __restrict__ cursor4,
                                                  const int* __restrict__ ell,
                                                  const float* __restrict__ bs2,
                                                  float* __restrict__ out) {
  const int node = blockIdx.x * 4 + (threadIdx.x >> 6);
  const int lane = threadIdx.x & 63;
  const int g  = lane >> 3;
  const int fl = lane & 7;

  const int4 c4 = *(const int4*)&cursor4[node * 4];
  const int rel = lane >> 4;
  const int idx = lane & 15;
  const int cr = (rel == 0) ? c4.x : (rel == 1) ? c4.y : (rel == 2) ? c4.z : c4.w;
  const int nslots = cr < 16 ? cr : 16;
  const bool valid = idx < nslots;

  int row = 0;
  float w = 0.f;
  if (valid) {
    const int src = ell[(size_t)node * 64 + lane];
    row = rel * NN + src;
    w = rsqrtf(fmaxf((float)cnt_out[row], 1.f)) * rsqrtf(fmaxf((float)cr, 1.f));
  }

  const unsigned long long mask = __ballot(valid);
  const int total = __popcll(mask);
  const int pos = __popcll(mask & ((1ull << lane) - 1ull));
  const int tgt = (valid ? pos : 63) << 2;
  const int crow = __builtin_amdgcn_ds_permute(tgt, row);
  const int cwb  = __builtin_amdgcn_ds_permute(tgt, __float_as_int(w));

  float acc[8];
#pragma unroll
  for (int j = 0; j < 8; ++j) acc[j] = 0.f;

  const int kmax = (total + 7) >> 3;  // wave-uniform trip count
  for (int k = 0; k < kmax; ++k) {
    const int e = g + k * 8;          // <= 63 always
    const int rowe = __shfl(crow, e);
    const float we = __int_as_float(__shfl(cwb, e));
    if (e < total) {
      const bf16x8 h = *(const bf16x8*)&H[(size_t)rowe * 64 + fl * 8];
#pragma unroll
      for (int j = 0; j < 8; ++j)
        acc[j] = fmaf(bf2f((unsigned short)h[j]), we, acc[j]);
    }
  }
#pragma unroll
  for (int j = 0; j < 8; ++j) {
    acc[j] += __shfl_xor(acc[j], 8);
    acc[j] += __shfl_xor(acc[j], 16);
    acc[j] += __shfl_xor(acc[j], 32);
  }
  if (g == 0) {
    const float4 c0 = *(const float4*)&bs2[fl * 8];
    const float4 c1 = *(const float4*)&bs2[fl * 8 + 4];
    float4 o0, o1;
    o0.x = acc[0] + c0.x; o0.y = acc[1] + c0.y; o0.z = acc[2] + c0.z; o0.w = acc[3] + c0.w;
    o1.x = acc[4] + c1.x; o1.y = acc[5] + c1.y; o1.z = acc[6] + c1.z; o1.w = acc[7] + c1.w;
    *(float4*)&out[(size_t)node * 64 + fl * 8]     = o0;
    *(float4*)&out[(size_t)node * 64 + fl * 8 + 4] = o1;
  }
}

// ---------------------------------------------------------------- launch
extern "C" void kernel_launch(void* const* d_in, const int* in_sizes, int n_in,
                              void* d_out, int out_size, void* d_ws, size_t ws_size,
                              hipStream_t stream) {
  const float* x     = (const float*)d_in[0];
  const int*   edges = (const int*)d_in[1];
  const float* W1    = (const float*)d_in[2];
  const float* b1    = (const float*)d_in[3];
  const float* W2    = (const float*)d_in[4];
  const float* b2    = (const float*)d_in[5];
  float* out = (float*)d_out;

  // ---- workspace layout (R18-proven ELL)
  unsigned short* xb   = (unsigned short*)d_ws;            // NN*128 bf16
  unsigned short* h1b  = xb;                               // reuse after layer1 GEMM
  unsigned short* Hbuf = xb + (size_t)NN * 128;            // NR*NN*128 bf16
  unsigned short* Wt1  = Hbuf + (size_t)NR * NN * 128;     // NR*128*128 bf16
  unsigned short* Wt2  = Wt1 + (size_t)NR * 128 * 128;     // NR*64*128 bf16
  int* cnt_out  = (int*)(Wt2 + (size_t)NR * 64 * 128);     // NR*NN
  int* cursor4  = cnt_out + (size_t)NR * NN;               // NN*4 (contiguous with cnt_out for zeroing)
  float* bs1    = (float*)(cursor4 + (size_t)NN * 4);      // 128
  float* bs2    = bs1 + 128;                               // 64
  int* ell      = (int*)(bs2 + 64);                        // NN*64

  // A) zero cnt_out+cursor4 + converts + bias sums
  phaseA_k<<<A_NBLK, 256, 0, stream>>>(x, W1, W2, b1, b2, cnt_out, xb, Wt1, Wt2, bs1, bs2);
  // B) gemm1 || prep (count + ELL insert)
  phaseB_ell_k<<<GEMMB + 2500, 256, 0, stream>>>(edges, xb, Wt1, Hbuf, cnt_out, cursor4, ell);
  // C) gather+bias+relu -> h1b (weights computed inline)
  gather1e_k<<<NN / 4, 256, 0, stream>>>(Hbuf, cnt_out, cursor4, ell, bs1, h1b);
  // D) layer-2 dual GEMM
  gemm_dual_k<<<dim3(128, 1, 2), 256, 0, stream>>>(h1b, Wt2, Hbuf);
  // E) gather+bias -> out
  gather2e_k<<<NN / 4, 256, 0, stream>>>(Hbuf, cnt_out, cursor4, ell, bs2, out);
}